// Round 2
// baseline (1732.604 us; speedup 1.0000x reference)
//
#include <hip/hip_runtime.h>

#define N_NODES 100000
#define E_EDGES 3200000
#define IN_CH 256
#define HID 32
#define OUT_CH 16

#define B_BUCKETS 250     // buckets over nodes
#define NPB 400           // nodes per bucket (250*400 = 100000 exactly)
#define CAP 20000         // LDS staging capacity (mean 12800, +60σ headroom)

// ---------------- phase 1: per-bucket edge counts ----------------

__global__ void k_bcount(const int* __restrict__ col, int* __restrict__ bcnt, int e) {
    __shared__ int h[B_BUCKETS];
    for (int i = threadIdx.x; i < B_BUCKETS; i += blockDim.x) h[i] = 0;
    __syncthreads();
    for (int i = blockIdx.x * blockDim.x + threadIdx.x; i < e; i += gridDim.x * blockDim.x)
        atomicAdd(&h[col[i] / NPB], 1);
    __syncthreads();
    for (int i = threadIdx.x; i < B_BUCKETS; i += blockDim.x)
        if (h[i]) atomicAdd(&bcnt[i], h[i]);
}

// ---------------- phase 2: scan bucket counts (1 block) ----------------

__global__ void k_bscan(const int* __restrict__ bcnt, int* __restrict__ bstart,
                        int* __restrict__ bcur) {
    __shared__ int a[256], b[256];
    int t = threadIdx.x;
    int myc = (t < B_BUCKETS) ? bcnt[t] : 0;
    a[t] = myc;
    __syncthreads();
    int* sp = a; int* dp = b;
    for (int off = 1; off < 256; off <<= 1) {
        dp[t] = sp[t] + ((t >= off) ? sp[t - off] : 0);
        __syncthreads();
        int* tm = sp; sp = dp; dp = tm;
    }
    int incl = sp[t];
    int excl = incl - myc;
    if (t < B_BUCKETS) { bstart[t] = excl; bcur[t] = excl; }
    if (t == B_BUCKETS - 1) bstart[B_BUCKETS] = incl;
}

// ---------------- phase 3: partition edges into buckets (packed u32) ----------------

__global__ void k_part(const int* __restrict__ row, const int* __restrict__ col,
                       int* __restrict__ bcur, unsigned* __restrict__ psrc, int e) {
    int i = blockIdx.x * blockDim.x + threadIdx.x;
    if (i >= e) return;
    int c = col[i];
    int b = c / NPB;
    int pos = atomicAdd(&bcur[b], 1);
    psrc[pos] = ((unsigned)(c - b * NPB) << 17) | (unsigned)row[i];
}

// ---------------- phase 4: within-bucket sort in LDS -> srow, deg, start, dis ----------------

__global__ __launch_bounds__(512) void k_bsort(const unsigned* __restrict__ psrc,
                                               const int* __restrict__ bstart,
                                               int* __restrict__ srow, int* __restrict__ deg,
                                               int* __restrict__ start, float* __restrict__ dis) {
    __shared__ unsigned buf[CAP];
    __shared__ int cnt[512];
    __shared__ int sa[512];
    __shared__ int sb[512];
    int b = blockIdx.x, t = threadIdx.x;
    int s0 = bstart[b], s1 = bstart[b + 1], len = s1 - s0;

    cnt[t] = 0;
    __syncthreads();
    for (int i = t; i < len; i += 512)
        atomicAdd(&cnt[psrc[s0 + i] >> 17], 1);
    __syncthreads();

    // inclusive scan of cnt[512] via Hillis-Steele (sa/sb ping-pong)
    sa[t] = cnt[t];
    __syncthreads();
    int* sp = sa; int* dp = sb;
    for (int off = 1; off < 512; off <<= 1) {
        dp[t] = sp[t] + ((t >= off) ? sp[t - off] : 0);
        __syncthreads();
        int* tm = sp; sp = dp; dp = tm;
    }
    int ex = sp[t] - cnt[t];   // exclusive prefix for node t
    __syncthreads();
    sa[t] = ex;                // sa = stable exclusive offsets
    sb[t] = ex;                // sb = cursors
    if (t < NPB) {
        int node = b * NPB + t;
        int d = cnt[t];
        deg[node] = d;
        start[node] = s0 + ex;
        dis[node] = rsqrtf((float)(d + 1));
    }
    __syncthreads();

    bool fits = (len <= CAP);
    for (int i = t; i < len; i += 512) {
        unsigned p = psrc[s0 + i];
        int cl = (int)(p >> 17);
        int pos = atomicAdd(&sb[cl], 1);
        if (fits) buf[pos] = p & 0x1FFFFu;
        else      srow[s0 + pos] = (int)(p & 0x1FFFFu);
    }
    __syncthreads();
    if (fits)
        for (int i = t; i < len; i += 512)
            srow[s0 + i] = (int)buf[i];
}

// ---------------- layer 1 GEMM: h0 = x @ W1  [N,256]x[256,32] ----------------

__global__ void k_gemm1(const float* __restrict__ x, const float* __restrict__ W1,
                        float* __restrict__ h0, int n) {
    int v = blockIdx.x * blockDim.x + threadIdx.x;
    if (v >= n) return;
    const float* xr = x + (size_t)v * IN_CH;
    float acc[HID];
#pragma unroll
    for (int c = 0; c < HID; ++c) acc[c] = 0.0f;
    for (int k = 0; k < IN_CH; k += 4) {
        float4 xv = *reinterpret_cast<const float4*>(xr + k);
        float xs[4] = {xv.x, xv.y, xv.z, xv.w};
#pragma unroll
        for (int j = 0; j < 4; ++j) {
#pragma unroll
            for (int c = 0; c < HID; ++c)
                acc[c] = fmaf(xs[j], W1[(k + j) * HID + c], acc[c]);
    }
    }
    float4* o = reinterpret_cast<float4*>(h0 + (size_t)v * HID);
#pragma unroll
    for (int q = 0; q < HID / 4; ++q)
        o[q] = make_float4(acc[q * 4 + 0], acc[q * 4 + 1], acc[q * 4 + 2], acc[q * 4 + 3]);
}

// ---------------- aggregation 1 (pull) + bias + relu ----------------

__global__ void k_agg1(const float* __restrict__ h0, const int* __restrict__ srow,
                       const int* __restrict__ start, const int* __restrict__ deg,
                       const float* __restrict__ dis, const float* __restrict__ b1,
                       float* __restrict__ h, int n) {
    int v = blockIdx.x * (blockDim.x >> 5) + (threadIdx.x >> 5);
    int c = threadIdx.x & 31;
    if (v >= n) return;
    int s = start[v];
    int d = deg[v];
    float a0 = 0.f, a1 = 0.f, a2 = 0.f, a3 = 0.f;
    int i = 0;
    for (; i + 4 <= d; i += 4) {
        int u0 = srow[s + i + 0];
        int u1 = srow[s + i + 1];
        int u2 = srow[s + i + 2];
        int u3 = srow[s + i + 3];
        a0 = fmaf(dis[u0], h0[(size_t)u0 * HID + c], a0);
        a1 = fmaf(dis[u1], h0[(size_t)u1 * HID + c], a1);
        a2 = fmaf(dis[u2], h0[(size_t)u2 * HID + c], a2);
        a3 = fmaf(dis[u3], h0[(size_t)u3 * HID + c], a3);
    }
    for (; i < d; ++i) {
        int u = srow[s + i];
        a0 = fmaf(dis[u], h0[(size_t)u * HID + c], a0);
    }
    float acc = (a0 + a1) + (a2 + a3);
    float dv = dis[v];
    float val = fmaf(dv, acc, dv * dv * h0[(size_t)v * HID + c]) + b1[c];
    h[(size_t)v * HID + c] = fmaxf(val, 0.0f);
}

// ---------------- layer 2+3 GEMM: t = h @ [Wmu | Wlv]  [N,32]x[32,32] ----------------

__global__ void k_gemm2(const float* __restrict__ h, const float* __restrict__ Wmu,
                        const float* __restrict__ Wlv, float* __restrict__ t, int n) {
    int v = blockIdx.x * blockDim.x + threadIdx.x;
    if (v >= n) return;
    const float* hr = h + (size_t)v * HID;
    float hreg[HID];
#pragma unroll
    for (int q = 0; q < HID / 4; ++q) {
        float4 hv = reinterpret_cast<const float4*>(hr)[q];
        hreg[q * 4 + 0] = hv.x; hreg[q * 4 + 1] = hv.y;
        hreg[q * 4 + 2] = hv.z; hreg[q * 4 + 3] = hv.w;
    }
    float am[OUT_CH], al[OUT_CH];
#pragma unroll
    for (int c = 0; c < OUT_CH; ++c) { am[c] = 0.f; al[c] = 0.f; }
#pragma unroll
    for (int k = 0; k < HID; ++k) {
#pragma unroll
        for (int c = 0; c < OUT_CH; ++c) {
            am[c] = fmaf(hreg[k], Wmu[k * OUT_CH + c], am[c]);
            al[c] = fmaf(hreg[k], Wlv[k * OUT_CH + c], al[c]);
        }
    }
    float* tr = t + (size_t)v * HID;
    float4* o = reinterpret_cast<float4*>(tr);
#pragma unroll
    for (int q = 0; q < OUT_CH / 4; ++q)
        o[q] = make_float4(am[q * 4], am[q * 4 + 1], am[q * 4 + 2], am[q * 4 + 3]);
#pragma unroll
    for (int q = 0; q < OUT_CH / 4; ++q)
        o[OUT_CH / 4 + q] = make_float4(al[q * 4], al[q * 4 + 1], al[q * 4 + 2], al[q * 4 + 3]);
}

// ---------------- aggregation 2 (pull) -> mu, logvar ----------------

__global__ void k_agg2(const float* __restrict__ t, const int* __restrict__ srow,
                       const int* __restrict__ start, const int* __restrict__ deg,
                       const float* __restrict__ dis, const float* __restrict__ bmu,
                       const float* __restrict__ blv, float* __restrict__ out, int n) {
    int v = blockIdx.x * (blockDim.x >> 5) + (threadIdx.x >> 5);
    int c = threadIdx.x & 31;
    if (v >= n) return;
    int s = start[v];
    int d = deg[v];
    float a0 = 0.f, a1 = 0.f, a2 = 0.f, a3 = 0.f;
    int i = 0;
    for (; i + 4 <= d; i += 4) {
        int u0 = srow[s + i + 0];
        int u1 = srow[s + i + 1];
        int u2 = srow[s + i + 2];
        int u3 = srow[s + i + 3];
        a0 = fmaf(dis[u0], t[(size_t)u0 * HID + c], a0);
        a1 = fmaf(dis[u1], t[(size_t)u1 * HID + c], a1);
        a2 = fmaf(dis[u2], t[(size_t)u2 * HID + c], a2);
        a3 = fmaf(dis[u3], t[(size_t)u3 * HID + c], a3);
    }
    for (; i < d; ++i) {
        int u = srow[s + i];
        a0 = fmaf(dis[u], t[(size_t)u * HID + c], a0);
    }
    float acc = (a0 + a1) + (a2 + a3);
    float dv = dis[v];
    float self = t[(size_t)v * HID + c];
    float bias = (c < OUT_CH) ? bmu[c] : blv[c - OUT_CH];
    float val = fmaf(dv, acc, dv * dv * self) + bias;
    if (c < OUT_CH)
        out[(size_t)v * OUT_CH + c] = val;
    else
        out[(size_t)N_NODES * OUT_CH + (size_t)v * OUT_CH + (c - OUT_CH)] = val;
}

// ---------------- launch ----------------

extern "C" void kernel_launch(void* const* d_in, const int* in_sizes, int n_in,
                              void* d_out, int out_size, void* d_ws, size_t ws_size,
                              hipStream_t stream) {
    const float* x   = (const float*)d_in[0];
    const int*   ei  = (const int*)d_in[1];
    const float* W1  = (const float*)d_in[2];
    const float* b1  = (const float*)d_in[3];
    const float* Wmu = (const float*)d_in[4];
    const float* bmu = (const float*)d_in[5];
    const float* Wlv = (const float*)d_in[6];
    const float* blv = (const float*)d_in[7];
    float* out = (float*)d_out;

    const int* row = ei;            // edge_index[0]
    const int* col = ei + E_EDGES;  // edge_index[1]

    char* w = (char*)d_ws;
    int*   bcnt   = (int*)w;  w += 1024;               // 250 used
    int*   bstart = (int*)w;  w += 1024;               // 251 used
    int*   bcur   = (int*)w;  w += 1024;               // 250 used
    int*   deg    = (int*)w;  w += (size_t)N_NODES * 4;
    float* dis    = (float*)w; w += (size_t)N_NODES * 4;
    int*   start  = (int*)w;  w += (size_t)N_NODES * 4;
    int*   srow   = (int*)w;  w += (size_t)E_EDGES * 4;
    unsigned* psrc = (unsigned*)w;                      // 12.8 MB, aliased:
    float* h0     = (float*)w; w += (size_t)N_NODES * HID * 4;  // h0 written after psrc dead
    float* h      = (float*)w; w += (size_t)N_NODES * HID * 4;
    float* t      = h0;  // reuse again: h0 dead after k_agg1

    hipMemsetAsync(bcnt, 0, 1024, stream);

    const int TB = 256;
    k_bcount<<<1024, TB, 0, stream>>>(col, bcnt, E_EDGES);
    k_bscan<<<1, 256, 0, stream>>>(bcnt, bstart, bcur);
    k_part<<<(E_EDGES + TB - 1) / TB, TB, 0, stream>>>(row, col, bcur, psrc, E_EDGES);
    k_bsort<<<B_BUCKETS, 512, 0, stream>>>(psrc, bstart, srow, deg, start, dis);
    k_gemm1<<<(N_NODES + TB - 1) / TB, TB, 0, stream>>>(x, W1, h0, N_NODES);
    k_agg1<<<(N_NODES + 7) / 8, TB, 0, stream>>>(h0, srow, start, deg, dis, b1, h, N_NODES);
    k_gemm2<<<(N_NODES + TB - 1) / TB, TB, 0, stream>>>(h, Wmu, Wlv, t, N_NODES);
    k_agg2<<<(N_NODES + 7) / 8, TB, 0, stream>>>(t, srow, start, deg, dis, bmu, blv, out, N_NODES);
}

// Round 3
// 292.629 us; speedup vs baseline: 5.9208x; 5.9208x over previous
//
#include <hip/hip_runtime.h>

#define N_NODES 100000
#define E_EDGES 3200000
#define IN_CH 256
#define HID 32
#define OUT_CH 16

#define B_BUCKETS 250     // buckets over nodes
#define NPB 400           // nodes per bucket (250*400 = 100000 exactly)
#define CAP 20000         // LDS staging capacity in k_bsort
#define PART_BLOCKS 512
#define PART_CHUNK ((E_EDGES + PART_BLOCKS - 1) / PART_BLOCKS)  // 6250

// ---------------- phase 1: per-bucket edge counts ----------------

__global__ void k_bcount(const int* __restrict__ col, int* __restrict__ bcnt, int e) {
    __shared__ int h[B_BUCKETS];
    for (int i = threadIdx.x; i < B_BUCKETS; i += blockDim.x) h[i] = 0;
    __syncthreads();
    for (int i = blockIdx.x * blockDim.x + threadIdx.x; i < e; i += gridDim.x * blockDim.x)
        atomicAdd(&h[col[i] / NPB], 1);
    __syncthreads();
    for (int i = threadIdx.x; i < B_BUCKETS; i += blockDim.x)
        if (h[i]) atomicAdd(&bcnt[i], h[i]);
}

// ---------------- phase 2: scan bucket counts (1 block) ----------------

__global__ void k_bscan(const int* __restrict__ bcnt, int* __restrict__ bstart,
                        int* __restrict__ bcur) {
    __shared__ int a[256], b[256];
    int t = threadIdx.x;
    int myc = (t < B_BUCKETS) ? bcnt[t] : 0;
    a[t] = myc;
    __syncthreads();
    int* sp = a; int* dp = b;
    for (int off = 1; off < 256; off <<= 1) {
        dp[t] = sp[t] + ((t >= off) ? sp[t - off] : 0);
        __syncthreads();
        int* tm = sp; sp = dp; dp = tm;
    }
    int incl = sp[t];
    int excl = incl - myc;
    if (t < B_BUCKETS) { bstart[t] = excl; bcur[t] = excl; }
    if (t == B_BUCKETS - 1) bstart[B_BUCKETS] = incl;
}

// ---------------- phase 3: partition edges into buckets (LDS-aggregated) ----------------

__global__ __launch_bounds__(256) void k_part(const int* __restrict__ row,
                                              const int* __restrict__ col,
                                              int* __restrict__ bcur,
                                              unsigned* __restrict__ psrc, int e) {
    __shared__ int hist[B_BUCKETS];
    __shared__ int base[B_BUCKETS];
    int lo = blockIdx.x * PART_CHUNK;
    int hi = min(e, lo + PART_CHUNK);
    if (lo >= hi) return;
    for (int i = threadIdx.x; i < B_BUCKETS; i += blockDim.x) hist[i] = 0;
    __syncthreads();
    // pass A: local histogram
    for (int i = lo + threadIdx.x; i < hi; i += blockDim.x)
        atomicAdd(&hist[col[i] / NPB], 1);
    __syncthreads();
    // reserve contiguous runs: one global atomic per (block, bucket)
    for (int i = threadIdx.x; i < B_BUCKETS; i += blockDim.x) {
        int h = hist[i];
        base[i] = h ? atomicAdd(&bcur[i], h) : 0;
    }
    __syncthreads();
    for (int i = threadIdx.x; i < B_BUCKETS; i += blockDim.x) hist[i] = 0; // reuse as cursor
    __syncthreads();
    // pass B: place edges (chunk is L2-hot from pass A)
    for (int i = lo + threadIdx.x; i < hi; i += blockDim.x) {
        int c = col[i];
        int b = c / NPB;
        int pos = base[b] + atomicAdd(&hist[b], 1);
        psrc[pos] = ((unsigned)(c - b * NPB) << 17) | (unsigned)row[i];
    }
}

// ---------------- phase 4: within-bucket sort in LDS -> srow, deg, start, dis ----------------

__global__ __launch_bounds__(512) void k_bsort(const unsigned* __restrict__ psrc,
                                               const int* __restrict__ bstart,
                                               int* __restrict__ srow, int* __restrict__ deg,
                                               int* __restrict__ start, float* __restrict__ dis) {
    __shared__ unsigned buf[CAP];
    __shared__ int cnt[512];
    __shared__ int sa[512];
    __shared__ int sb[512];
    int b = blockIdx.x, t = threadIdx.x;
    int s0 = bstart[b], s1 = bstart[b + 1], len = s1 - s0;

    cnt[t] = 0;
    __syncthreads();
    for (int i = t; i < len; i += 512)
        atomicAdd(&cnt[psrc[s0 + i] >> 17], 1);
    __syncthreads();

    sa[t] = cnt[t];
    __syncthreads();
    int* sp = sa; int* dp = sb;
    for (int off = 1; off < 512; off <<= 1) {
        dp[t] = sp[t] + ((t >= off) ? sp[t - off] : 0);
        __syncthreads();
        int* tm = sp; sp = dp; dp = tm;
    }
    int ex = sp[t] - cnt[t];
    __syncthreads();
    sa[t] = ex;
    sb[t] = ex;
    if (t < NPB) {
        int node = b * NPB + t;
        int d = cnt[t];
        deg[node] = d;
        start[node] = s0 + ex;
        dis[node] = rsqrtf((float)(d + 1));
    }
    __syncthreads();

    bool fits = (len <= CAP);
    for (int i = t; i < len; i += 512) {
        unsigned p = psrc[s0 + i];
        int cl = (int)(p >> 17);
        int pos = atomicAdd(&sb[cl], 1);
        if (fits) buf[pos] = p & 0x1FFFFu;
        else      srow[s0 + pos] = (int)(p & 0x1FFFFu);
    }
    __syncthreads();
    if (fits)
        for (int i = t; i < len; i += 512)
            srow[s0 + i] = (int)buf[i];
}

// ---------------- layer 1 GEMM: h0 = x @ W1  [N,256]x[256,32] ----------------

__global__ void k_gemm1(const float* __restrict__ x, const float* __restrict__ W1,
                        float* __restrict__ h0, int n) {
    int v = blockIdx.x * blockDim.x + threadIdx.x;
    if (v >= n) return;
    const float* xr = x + (size_t)v * IN_CH;
    float acc[HID];
#pragma unroll
    for (int c = 0; c < HID; ++c) acc[c] = 0.0f;
    for (int k = 0; k < IN_CH; k += 4) {
        float4 xv = *reinterpret_cast<const float4*>(xr + k);
        float xs[4] = {xv.x, xv.y, xv.z, xv.w};
#pragma unroll
        for (int j = 0; j < 4; ++j) {
#pragma unroll
            for (int c = 0; c < HID; ++c)
                acc[c] = fmaf(xs[j], W1[(k + j) * HID + c], acc[c]);
        }
    }
    float4* o = reinterpret_cast<float4*>(h0 + (size_t)v * HID);
#pragma unroll
    for (int q = 0; q < HID / 4; ++q)
        o[q] = make_float4(acc[q * 4 + 0], acc[q * 4 + 1], acc[q * 4 + 2], acc[q * 4 + 3]);
}

// ---------------- aggregation 1 (pull) + bias + relu ----------------

__global__ void k_agg1(const float* __restrict__ h0, const int* __restrict__ srow,
                       const int* __restrict__ start, const int* __restrict__ deg,
                       const float* __restrict__ dis, const float* __restrict__ b1,
                       float* __restrict__ h, int n) {
    int v = blockIdx.x * (blockDim.x >> 5) + (threadIdx.x >> 5);
    int c = threadIdx.x & 31;
    if (v >= n) return;
    int s = start[v];
    int d = deg[v];
    float a0 = 0.f, a1 = 0.f, a2 = 0.f, a3 = 0.f;
    int i = 0;
    for (; i + 4 <= d; i += 4) {
        int u0 = srow[s + i + 0];
        int u1 = srow[s + i + 1];
        int u2 = srow[s + i + 2];
        int u3 = srow[s + i + 3];
        a0 = fmaf(dis[u0], h0[(size_t)u0 * HID + c], a0);
        a1 = fmaf(dis[u1], h0[(size_t)u1 * HID + c], a1);
        a2 = fmaf(dis[u2], h0[(size_t)u2 * HID + c], a2);
        a3 = fmaf(dis[u3], h0[(size_t)u3 * HID + c], a3);
    }
    for (; i < d; ++i) {
        int u = srow[s + i];
        a0 = fmaf(dis[u], h0[(size_t)u * HID + c], a0);
    }
    float acc = (a0 + a1) + (a2 + a3);
    float dv = dis[v];
    float val = fmaf(dv, acc, dv * dv * h0[(size_t)v * HID + c]) + b1[c];
    h[(size_t)v * HID + c] = fmaxf(val, 0.0f);
}

// ---------------- layer 2+3 GEMM: t = h @ [Wmu | Wlv]  [N,32]x[32,32] ----------------

__global__ void k_gemm2(const float* __restrict__ h, const float* __restrict__ Wmu,
                        const float* __restrict__ Wlv, float* __restrict__ t, int n) {
    int v = blockIdx.x * blockDim.x + threadIdx.x;
    if (v >= n) return;
    const float* hr = h + (size_t)v * HID;
    float hreg[HID];
#pragma unroll
    for (int q = 0; q < HID / 4; ++q) {
        float4 hv = reinterpret_cast<const float4*>(hr)[q];
        hreg[q * 4 + 0] = hv.x; hreg[q * 4 + 1] = hv.y;
        hreg[q * 4 + 2] = hv.z; hreg[q * 4 + 3] = hv.w;
    }
    float am[OUT_CH], al[OUT_CH];
#pragma unroll
    for (int c = 0; c < OUT_CH; ++c) { am[c] = 0.f; al[c] = 0.f; }
#pragma unroll
    for (int k = 0; k < HID; ++k) {
#pragma unroll
        for (int c = 0; c < OUT_CH; ++c) {
            am[c] = fmaf(hreg[k], Wmu[k * OUT_CH + c], am[c]);
            al[c] = fmaf(hreg[k], Wlv[k * OUT_CH + c], al[c]);
        }
    }
    float* tr = t + (size_t)v * HID;
    float4* o = reinterpret_cast<float4*>(tr);
#pragma unroll
    for (int q = 0; q < OUT_CH / 4; ++q)
        o[q] = make_float4(am[q * 4], am[q * 4 + 1], am[q * 4 + 2], am[q * 4 + 3]);
#pragma unroll
    for (int q = 0; q < OUT_CH / 4; ++q)
        o[OUT_CH / 4 + q] = make_float4(al[q * 4], al[q * 4 + 1], al[q * 4 + 2], al[q * 4 + 3]);
}

// ---------------- aggregation 2 (pull) -> mu, logvar ----------------

__global__ void k_agg2(const float* __restrict__ t, const int* __restrict__ srow,
                       const int* __restrict__ start, const int* __restrict__ deg,
                       const float* __restrict__ dis, const float* __restrict__ bmu,
                       const float* __restrict__ blv, float* __restrict__ out, int n) {
    int v = blockIdx.x * (blockDim.x >> 5) + (threadIdx.x >> 5);
    int c = threadIdx.x & 31;
    if (v >= n) return;
    int s = start[v];
    int d = deg[v];
    float a0 = 0.f, a1 = 0.f, a2 = 0.f, a3 = 0.f;
    int i = 0;
    for (; i + 4 <= d; i += 4) {
        int u0 = srow[s + i + 0];
        int u1 = srow[s + i + 1];
        int u2 = srow[s + i + 2];
        int u3 = srow[s + i + 3];
        a0 = fmaf(dis[u0], t[(size_t)u0 * HID + c], a0);
        a1 = fmaf(dis[u1], t[(size_t)u1 * HID + c], a1);
        a2 = fmaf(dis[u2], t[(size_t)u2 * HID + c], a2);
        a3 = fmaf(dis[u3], t[(size_t)u3 * HID + c], a3);
    }
    for (; i < d; ++i) {
        int u = srow[s + i];
        a0 = fmaf(dis[u], t[(size_t)u * HID + c], a0);
    }
    float acc = (a0 + a1) + (a2 + a3);
    float dv = dis[v];
    float self = t[(size_t)v * HID + c];
    float bias = (c < OUT_CH) ? bmu[c] : blv[c - OUT_CH];
    float val = fmaf(dv, acc, dv * dv * self) + bias;
    if (c < OUT_CH)
        out[(size_t)v * OUT_CH + c] = val;
    else
        out[(size_t)N_NODES * OUT_CH + (size_t)v * OUT_CH + (c - OUT_CH)] = val;
}

// ---------------- launch ----------------

extern "C" void kernel_launch(void* const* d_in, const int* in_sizes, int n_in,
                              void* d_out, int out_size, void* d_ws, size_t ws_size,
                              hipStream_t stream) {
    const float* x   = (const float*)d_in[0];
    const int*   ei  = (const int*)d_in[1];
    const float* W1  = (const float*)d_in[2];
    const float* b1  = (const float*)d_in[3];
    const float* Wmu = (const float*)d_in[4];
    const float* bmu = (const float*)d_in[5];
    const float* Wlv = (const float*)d_in[6];
    const float* blv = (const float*)d_in[7];
    float* out = (float*)d_out;

    const int* row = ei;            // edge_index[0]
    const int* col = ei + E_EDGES;  // edge_index[1]

    char* w = (char*)d_ws;
    int*   bcnt   = (int*)w;  w += 1024;               // 250 used
    int*   bstart = (int*)w;  w += 1024;               // 251 used
    int*   bcur   = (int*)w;  w += 1024;               // 250 used
    int*   deg    = (int*)w;  w += (size_t)N_NODES * 4;
    float* dis    = (float*)w; w += (size_t)N_NODES * 4;
    int*   start  = (int*)w;  w += (size_t)N_NODES * 4;
    int*   srow   = (int*)w;  w += (size_t)E_EDGES * 4;
    unsigned* psrc = (unsigned*)w;                      // 12.8 MB, aliased with h0:
    float* h0     = (float*)w; w += (size_t)N_NODES * HID * 4;  // h0 written after psrc dead
    float* h      = (float*)w; w += (size_t)N_NODES * HID * 4;
    float* t      = h0;  // reuse again: h0 dead after k_agg1

    hipMemsetAsync(bcnt, 0, 1024, stream);

    const int TB = 256;
    k_bcount<<<1024, TB, 0, stream>>>(col, bcnt, E_EDGES);
    k_bscan<<<1, 256, 0, stream>>>(bcnt, bstart, bcur);
    k_part<<<PART_BLOCKS, 256, 0, stream>>>(row, col, bcur, psrc, E_EDGES);
    k_bsort<<<B_BUCKETS, 512, 0, stream>>>(psrc, bstart, srow, deg, start, dis);
    k_gemm1<<<(N_NODES + TB - 1) / TB, TB, 0, stream>>>(x, W1, h0, N_NODES);
    k_agg1<<<(N_NODES + 7) / 8, TB, 0, stream>>>(h0, srow, start, deg, dis, b1, h, N_NODES);
    k_gemm2<<<(N_NODES + TB - 1) / TB, TB, 0, stream>>>(h, Wmu, Wlv, t, N_NODES);
    k_agg2<<<(N_NODES + 7) / 8, TB, 0, stream>>>(t, srow, start, deg, dis, bmu, blv, out, N_NODES);
}

// Round 4
// 275.142 us; speedup vs baseline: 6.2971x; 1.0636x over previous
//
#include <hip/hip_runtime.h>

#define N_NODES 100000
#define E_EDGES 3200000
#define IN_CH 256
#define HID 32
#define OUT_CH 16

#define B_BUCKETS 250     // buckets over nodes
#define NPB 400           // nodes per bucket (250*400 = 100000 exactly)
#define CAP 20000         // LDS staging capacity in k_bsort
#define PART_BLOCKS 512
#define PART_CHUNK ((E_EDGES + PART_BLOCKS - 1) / PART_BLOCKS)  // 6250

// ---------------- phase 1: per-bucket edge counts ----------------

__global__ void k_bcount(const int* __restrict__ col, int* __restrict__ bcnt, int e) {
    __shared__ int h[B_BUCKETS];
    for (int i = threadIdx.x; i < B_BUCKETS; i += blockDim.x) h[i] = 0;
    __syncthreads();
    for (int i = blockIdx.x * blockDim.x + threadIdx.x; i < e; i += gridDim.x * blockDim.x)
        atomicAdd(&h[col[i] / NPB], 1);
    __syncthreads();
    for (int i = threadIdx.x; i < B_BUCKETS; i += blockDim.x)
        if (h[i]) atomicAdd(&bcnt[i], h[i]);
}

// ---------------- phase 2: scan bucket counts (1 block) ----------------

__global__ void k_bscan(const int* __restrict__ bcnt, int* __restrict__ bstart,
                        int* __restrict__ bcur) {
    __shared__ int a[256], b[256];
    int t = threadIdx.x;
    int myc = (t < B_BUCKETS) ? bcnt[t] : 0;
    a[t] = myc;
    __syncthreads();
    int* sp = a; int* dp = b;
    for (int off = 1; off < 256; off <<= 1) {
        dp[t] = sp[t] + ((t >= off) ? sp[t - off] : 0);
        __syncthreads();
        int* tm = sp; sp = dp; dp = tm;
    }
    int incl = sp[t];
    int excl = incl - myc;
    if (t < B_BUCKETS) { bstart[t] = excl; bcur[t] = excl; }
    if (t == B_BUCKETS - 1) bstart[B_BUCKETS] = incl;
}

// ---------------- phase 3: partition edges into buckets (LDS-aggregated) ----------------

__global__ __launch_bounds__(256) void k_part(const int* __restrict__ row,
                                              const int* __restrict__ col,
                                              int* __restrict__ bcur,
                                              unsigned* __restrict__ psrc, int e) {
    __shared__ int hist[B_BUCKETS];
    __shared__ int base[B_BUCKETS];
    int lo = blockIdx.x * PART_CHUNK;
    int hi = min(e, lo + PART_CHUNK);
    if (lo >= hi) return;
    for (int i = threadIdx.x; i < B_BUCKETS; i += blockDim.x) hist[i] = 0;
    __syncthreads();
    for (int i = lo + threadIdx.x; i < hi; i += blockDim.x)
        atomicAdd(&hist[col[i] / NPB], 1);
    __syncthreads();
    for (int i = threadIdx.x; i < B_BUCKETS; i += blockDim.x) {
        int h = hist[i];
        base[i] = h ? atomicAdd(&bcur[i], h) : 0;
    }
    __syncthreads();
    for (int i = threadIdx.x; i < B_BUCKETS; i += blockDim.x) hist[i] = 0; // reuse as cursor
    __syncthreads();
    for (int i = lo + threadIdx.x; i < hi; i += blockDim.x) {
        int c = col[i];
        int b = c / NPB;
        int pos = base[b] + atomicAdd(&hist[b], 1);
        psrc[pos] = ((unsigned)(c - b * NPB) << 17) | (unsigned)row[i];
    }
}

// ---------------- phase 4: within-bucket sort in LDS -> srow, deg, start, dis ----------------

__global__ __launch_bounds__(512) void k_bsort(const unsigned* __restrict__ psrc,
                                               const int* __restrict__ bstart,
                                               int* __restrict__ srow, int* __restrict__ deg,
                                               int* __restrict__ start, float* __restrict__ dis) {
    __shared__ unsigned buf[CAP];
    __shared__ int cnt[512];
    __shared__ int sa[512];
    __shared__ int sb[512];
    int b = blockIdx.x, t = threadIdx.x;
    int s0 = bstart[b], s1 = bstart[b + 1], len = s1 - s0;

    cnt[t] = 0;
    __syncthreads();
    for (int i = t; i < len; i += 512)
        atomicAdd(&cnt[psrc[s0 + i] >> 17], 1);
    __syncthreads();

    sa[t] = cnt[t];
    __syncthreads();
    int* sp = sa; int* dp = sb;
    for (int off = 1; off < 512; off <<= 1) {
        dp[t] = sp[t] + ((t >= off) ? sp[t - off] : 0);
        __syncthreads();
        int* tm = sp; sp = dp; dp = tm;
    }
    int ex = sp[t] - cnt[t];
    __syncthreads();
    sa[t] = ex;
    sb[t] = ex;
    if (t < NPB) {
        int node = b * NPB + t;
        int d = cnt[t];
        deg[node] = d;
        start[node] = s0 + ex;
        dis[node] = rsqrtf((float)(d + 1));
    }
    __syncthreads();

    bool fits = (len <= CAP);
    for (int i = t; i < len; i += 512) {
        unsigned p = psrc[s0 + i];
        int cl = (int)(p >> 17);
        int pos = atomicAdd(&sb[cl], 1);
        if (fits) buf[pos] = p & 0x1FFFFu;
        else      srow[s0 + pos] = (int)(p & 0x1FFFFu);
    }
    __syncthreads();
    if (fits)
        for (int i = t; i < len; i += 512)
            srow[s0 + i] = (int)buf[i];
}

// ---------------- layer 1 GEMM: h0 = x @ W1, LDS-staged, K split over 4 waves ----------------
// 64 nodes/block, 4 waves; chunk = 64 k's; x staged transposed xt[k][node] (pad 65).

#define G1_NODES 64
#define G1_KC 64
#define G1_NCHUNK (IN_CH / G1_KC)   // 4

__global__ __launch_bounds__(256) void k_gemm1(const float* __restrict__ x,
                                               const float* __restrict__ W1,
                                               float* __restrict__ h0, int n) {
    __shared__ float lds[3 * G1_NODES * 33];   // 6336 floats: xt (64*65) and reduction buffer
    float (*xt)[G1_NODES + 1] = (float (*)[G1_NODES + 1])lds;

    int tid = threadIdx.x;
    int wv = __builtin_amdgcn_readfirstlane(tid >> 6);  // wave id 0..3
    int lane = tid & 63;
    int vbase = blockIdx.x * G1_NODES;

    float4 g[4];
#pragma unroll
    for (int it = 0; it < 4; ++it) {                    // prologue: load chunk 0
        int f = it * 256 + tid;
        int nl = f >> 4, q = f & 15;
        int v = vbase + nl; if (v >= n) v = n - 1;
        g[it] = *reinterpret_cast<const float4*>(x + (size_t)v * IN_CH + q * 4);
    }

    float acc[HID];
#pragma unroll
    for (int c = 0; c < HID; ++c) acc[c] = 0.f;

    for (int ch = 0; ch < G1_NCHUNK; ++ch) {
        __syncthreads();                                // all waves done reading xt
#pragma unroll
        for (int it = 0; it < 4; ++it) {                // reg -> LDS transposed
            int f = it * 256 + tid;
            int nl = f >> 4, q = f & 15;
            xt[q * 4 + 0][nl] = g[it].x;
            xt[q * 4 + 1][nl] = g[it].y;
            xt[q * 4 + 2][nl] = g[it].z;
            xt[q * 4 + 3][nl] = g[it].w;
        }
        __syncthreads();
        if (ch + 1 < G1_NCHUNK) {                       // prefetch next chunk (in flight during compute)
#pragma unroll
            for (int it = 0; it < 4; ++it) {
                int f = it * 256 + tid;
                int nl = f >> 4, q = f & 15;
                int v = vbase + nl; if (v >= n) v = n - 1;
                g[it] = *reinterpret_cast<const float4*>(
                    x + (size_t)v * IN_CH + (ch + 1) * G1_KC + q * 4);
            }
        }
        // wave wv computes k-sub [wv*16, wv*16+16) of this chunk for node = lane
#pragma unroll
        for (int j = 0; j < 16; ++j) {
            int kk = ch * G1_KC + wv * 16 + j;
            float xs = xt[wv * 16 + j][lane];
            const float* wrow = W1 + kk * HID;          // wave-uniform -> s_load
#pragma unroll
            for (int c = 0; c < HID; ++c)
                acc[c] = fmaf(xs, wrow[c], acc[c]);
        }
    }

    // cross-wave reduction: waves 1..3 dump partials, wave 0 reduces + stores
    __syncthreads();
    if (wv > 0) {
        float* dst = lds + (wv - 1) * (G1_NODES * 33) + lane * 33;
#pragma unroll
        for (int c = 0; c < HID; ++c) dst[c] = acc[c];
    }
    __syncthreads();
    if (wv == 0) {
        int v = vbase + lane;
        if (v < n) {
#pragma unroll
            for (int p = 0; p < 3; ++p) {
                const float* srcp = lds + p * (G1_NODES * 33) + lane * 33;
#pragma unroll
                for (int c = 0; c < HID; ++c) acc[c] += srcp[c];
            }
            float4* o = reinterpret_cast<float4*>(h0 + (size_t)v * HID);
#pragma unroll
            for (int q = 0; q < HID / 4; ++q)
                o[q] = make_float4(acc[q * 4], acc[q * 4 + 1], acc[q * 4 + 2], acc[q * 4 + 3]);
        }
    }
}

// ---------------- aggregation 1 (pull) + bias + relu + FUSED layer-2/3 GEMM ----------------
// 8 nodes per 256-thread block, 32 lanes per node (lane = hidden channel).
// After relu, t[v] = h_row @ [Wmu | Wlv] computed via LDS broadcast (saves h round-trip).

__global__ __launch_bounds__(256) void k_agg1(const float* __restrict__ h0,
                                              const int* __restrict__ srow,
                                              const int* __restrict__ start,
                                              const int* __restrict__ deg,
                                              const float* __restrict__ dis,
                                              const float* __restrict__ b1,
                                              const float* __restrict__ Wmu,
                                              const float* __restrict__ Wlv,
                                              float* __restrict__ t, int n) {
    __shared__ float hbuf[8][33];
    __shared__ float wc[32][33];   // combined [Wmu | Wlv], wc[c][c']
    int tid = threadIdx.x;
#pragma unroll
    for (int i = tid; i < 1024; i += 256) {
        int cc = i >> 5, cp = i & 31;
        wc[cc][cp] = (cp < OUT_CH) ? Wmu[cc * OUT_CH + cp] : Wlv[cc * OUT_CH + (cp - OUT_CH)];
    }
    int g = tid >> 5;
    int c = tid & 31;
    int v = blockIdx.x * 8 + g;
    __syncthreads();

    float val = 0.f;
    if (v < n) {
        int s = start[v];
        int d = deg[v];
        float a0 = 0.f, a1 = 0.f, a2 = 0.f, a3 = 0.f;
        int i = 0;
        for (; i + 4 <= d; i += 4) {
            int u0 = srow[s + i + 0];
            int u1 = srow[s + i + 1];
            int u2 = srow[s + i + 2];
            int u3 = srow[s + i + 3];
            a0 = fmaf(dis[u0], h0[(size_t)u0 * HID + c], a0);
            a1 = fmaf(dis[u1], h0[(size_t)u1 * HID + c], a1);
            a2 = fmaf(dis[u2], h0[(size_t)u2 * HID + c], a2);
            a3 = fmaf(dis[u3], h0[(size_t)u3 * HID + c], a3);
        }
        for (; i < d; ++i) {
            int u = srow[s + i];
            a0 = fmaf(dis[u], h0[(size_t)u * HID + c], a0);
        }
        float acc = (a0 + a1) + (a2 + a3);
        float dv = dis[v];
        val = fmaf(dv, acc, dv * dv * h0[(size_t)v * HID + c]) + b1[c];
        val = fmaxf(val, 0.0f);
    }
    hbuf[g][c] = val;
    __syncthreads();
    if (v < n) {
        float tm = 0.f;
#pragma unroll
        for (int k = 0; k < 32; ++k)
            tm = fmaf(hbuf[g][k], wc[k][c], tm);
        t[(size_t)v * HID + c] = tm;
    }
}

// ---------------- aggregation 2 (pull) -> mu, logvar ----------------

__global__ void k_agg2(const float* __restrict__ t, const int* __restrict__ srow,
                       const int* __restrict__ start, const int* __restrict__ deg,
                       const float* __restrict__ dis, const float* __restrict__ bmu,
                       const float* __restrict__ blv, float* __restrict__ out, int n) {
    int v = blockIdx.x * (blockDim.x >> 5) + (threadIdx.x >> 5);
    int c = threadIdx.x & 31;
    if (v >= n) return;
    int s = start[v];
    int d = deg[v];
    float a0 = 0.f, a1 = 0.f, a2 = 0.f, a3 = 0.f;
    int i = 0;
    for (; i + 4 <= d; i += 4) {
        int u0 = srow[s + i + 0];
        int u1 = srow[s + i + 1];
        int u2 = srow[s + i + 2];
        int u3 = srow[s + i + 3];
        a0 = fmaf(dis[u0], t[(size_t)u0 * HID + c], a0);
        a1 = fmaf(dis[u1], t[(size_t)u1 * HID + c], a1);
        a2 = fmaf(dis[u2], t[(size_t)u2 * HID + c], a2);
        a3 = fmaf(dis[u3], t[(size_t)u3 * HID + c], a3);
    }
    for (; i < d; ++i) {
        int u = srow[s + i];
        a0 = fmaf(dis[u], t[(size_t)u * HID + c], a0);
    }
    float acc = (a0 + a1) + (a2 + a3);
    float dv = dis[v];
    float self = t[(size_t)v * HID + c];
    float bias = (c < OUT_CH) ? bmu[c] : blv[c - OUT_CH];
    float val = fmaf(dv, acc, dv * dv * self) + bias;
    if (c < OUT_CH)
        out[(size_t)v * OUT_CH + c] = val;
    else
        out[(size_t)N_NODES * OUT_CH + (size_t)v * OUT_CH + (c - OUT_CH)] = val;
}

// ---------------- launch ----------------

extern "C" void kernel_launch(void* const* d_in, const int* in_sizes, int n_in,
                              void* d_out, int out_size, void* d_ws, size_t ws_size,
                              hipStream_t stream) {
    const float* x   = (const float*)d_in[0];
    const int*   ei  = (const int*)d_in[1];
    const float* W1  = (const float*)d_in[2];
    const float* b1  = (const float*)d_in[3];
    const float* Wmu = (const float*)d_in[4];
    const float* bmu = (const float*)d_in[5];
    const float* Wlv = (const float*)d_in[6];
    const float* blv = (const float*)d_in[7];
    float* out = (float*)d_out;

    const int* row = ei;            // edge_index[0]
    const int* col = ei + E_EDGES;  // edge_index[1]

    char* w = (char*)d_ws;
    int*   bcnt   = (int*)w;  w += 1024;
    int*   bstart = (int*)w;  w += 1024;
    int*   bcur   = (int*)w;  w += 1024;
    int*   deg    = (int*)w;  w += (size_t)N_NODES * 4;
    float* dis    = (float*)w; w += (size_t)N_NODES * 4;
    int*   start  = (int*)w;  w += (size_t)N_NODES * 4;
    int*   srow   = (int*)w;  w += (size_t)E_EDGES * 4;
    unsigned* psrc = (unsigned*)w;                      // aliased with h0 (psrc dead before h0 written)
    float* h0     = (float*)w; w += (size_t)N_NODES * HID * 4;
    float* t      = (float*)w; w += (size_t)N_NODES * HID * 4;  // agg1 reads h0, writes t: no alias

    hipMemsetAsync(bcnt, 0, 1024, stream);

    const int TB = 256;
    k_bcount<<<1024, TB, 0, stream>>>(col, bcnt, E_EDGES);
    k_bscan<<<1, 256, 0, stream>>>(bcnt, bstart, bcur);
    k_part<<<PART_BLOCKS, 256, 0, stream>>>(row, col, bcur, psrc, E_EDGES);
    k_bsort<<<B_BUCKETS, 512, 0, stream>>>(psrc, bstart, srow, deg, start, dis);
    k_gemm1<<<(N_NODES + G1_NODES - 1) / G1_NODES, 256, 0, stream>>>(x, W1, h0, N_NODES);
    k_agg1<<<(N_NODES + 7) / 8, TB, 0, stream>>>(h0, srow, start, deg, dis, b1, Wmu, Wlv, t, N_NODES);
    k_agg2<<<(N_NODES + 7) / 8, TB, 0, stream>>>(t, srow, start, deg, dis, bmu, blv, out, N_NODES);
}

// Round 5
// 252.546 us; speedup vs baseline: 6.8606x; 1.0895x over previous
//
#include <hip/hip_runtime.h>

#define N_NODES 100000
#define E_EDGES 3200000
#define IN_CH 256
#define HID 32
#define OUT_CH 16

#define B_BUCKETS 250     // buckets over nodes
#define NPB 400           // nodes per bucket (250*400 = 100000 exactly)
#define CAP 20000         // LDS staging capacity in k_bsort
#define PART_BLOCKS 512
#define PART_CHUNK ((E_EDGES + PART_BLOCKS - 1) / PART_BLOCKS)  // 6250

// ---------------- phase 1: per-bucket edge counts ----------------

__global__ void k_bcount(const int* __restrict__ col, int* __restrict__ bcnt, int e) {
    __shared__ int h[B_BUCKETS];
    for (int i = threadIdx.x; i < B_BUCKETS; i += blockDim.x) h[i] = 0;
    __syncthreads();
    for (int i = blockIdx.x * blockDim.x + threadIdx.x; i < e; i += gridDim.x * blockDim.x)
        atomicAdd(&h[col[i] / NPB], 1);
    __syncthreads();
    for (int i = threadIdx.x; i < B_BUCKETS; i += blockDim.x)
        if (h[i]) atomicAdd(&bcnt[i], h[i]);
}

// ---------------- phase 2: scan bucket counts (1 block) ----------------

__global__ void k_bscan(const int* __restrict__ bcnt, int* __restrict__ bstart,
                        int* __restrict__ bcur) {
    __shared__ int a[256], b[256];
    int t = threadIdx.x;
    int myc = (t < B_BUCKETS) ? bcnt[t] : 0;
    a[t] = myc;
    __syncthreads();
    int* sp = a; int* dp = b;
    for (int off = 1; off < 256; off <<= 1) {
        dp[t] = sp[t] + ((t >= off) ? sp[t - off] : 0);
        __syncthreads();
        int* tm = sp; sp = dp; dp = tm;
    }
    int incl = sp[t];
    int excl = incl - myc;
    if (t < B_BUCKETS) { bstart[t] = excl; bcur[t] = excl; }
    if (t == B_BUCKETS - 1) bstart[B_BUCKETS] = incl;
}

// ---------------- phase 3: partition edges into buckets (LDS-aggregated) ----------------

__global__ __launch_bounds__(256) void k_part(const int* __restrict__ row,
                                              const int* __restrict__ col,
                                              int* __restrict__ bcur,
                                              unsigned* __restrict__ psrc, int e) {
    __shared__ int hist[B_BUCKETS];
    __shared__ int base[B_BUCKETS];
    int lo = blockIdx.x * PART_CHUNK;
    int hi = min(e, lo + PART_CHUNK);
    if (lo >= hi) return;
    for (int i = threadIdx.x; i < B_BUCKETS; i += blockDim.x) hist[i] = 0;
    __syncthreads();
    for (int i = lo + threadIdx.x; i < hi; i += blockDim.x)
        atomicAdd(&hist[col[i] / NPB], 1);
    __syncthreads();
    for (int i = threadIdx.x; i < B_BUCKETS; i += blockDim.x) {
        int h = hist[i];
        base[i] = h ? atomicAdd(&bcur[i], h) : 0;
    }
    __syncthreads();
    for (int i = threadIdx.x; i < B_BUCKETS; i += blockDim.x) hist[i] = 0; // reuse as cursor
    __syncthreads();
    for (int i = lo + threadIdx.x; i < hi; i += blockDim.x) {
        int c = col[i];
        int b = c / NPB;
        int pos = base[b] + atomicAdd(&hist[b], 1);
        psrc[pos] = ((unsigned)(c - b * NPB) << 17) | (unsigned)row[i];
    }
}

// ---------------- phase 4: within-bucket sort in LDS -> srow, deg, start, dis ----------------

__global__ __launch_bounds__(512) void k_bsort(const unsigned* __restrict__ psrc,
                                               const int* __restrict__ bstart,
                                               int* __restrict__ srow, int* __restrict__ deg,
                                               int* __restrict__ start, float* __restrict__ dis) {
    __shared__ unsigned buf[CAP];
    __shared__ int cnt[512];
    __shared__ int sa[512];
    __shared__ int sb[512];
    int b = blockIdx.x, t = threadIdx.x;
    int s0 = bstart[b], s1 = bstart[b + 1], len = s1 - s0;

    cnt[t] = 0;
    __syncthreads();
    for (int i = t; i < len; i += 512)
        atomicAdd(&cnt[psrc[s0 + i] >> 17], 1);
    __syncthreads();

    sa[t] = cnt[t];
    __syncthreads();
    int* sp = sa; int* dp = sb;
    for (int off = 1; off < 512; off <<= 1) {
        dp[t] = sp[t] + ((t >= off) ? sp[t - off] : 0);
        __syncthreads();
        int* tm = sp; sp = dp; dp = tm;
    }
    int ex = sp[t] - cnt[t];
    __syncthreads();
    sa[t] = ex;
    sb[t] = ex;
    if (t < NPB) {
        int node = b * NPB + t;
        int d = cnt[t];
        deg[node] = d;
        start[node] = s0 + ex;
        dis[node] = rsqrtf((float)(d + 1));
    }
    __syncthreads();

    bool fits = (len <= CAP);
    for (int i = t; i < len; i += 512) {
        unsigned p = psrc[s0 + i];
        int cl = (int)(p >> 17);
        int pos = atomicAdd(&sb[cl], 1);
        if (fits) buf[pos] = p & 0x1FFFFu;
        else      srow[s0 + pos] = (int)(p & 0x1FFFFu);
    }
    __syncthreads();
    if (fits)
        for (int i = t; i < len; i += 512)
            srow[s0 + i] = (int)buf[i];
}

// ---------------- layer 1 GEMM: h0s = dis * (x @ W1), LDS-staged ----------------

#define G1_NODES 64
#define G1_KC 64
#define G1_NCHUNK (IN_CH / G1_KC)   // 4

__global__ __launch_bounds__(256) void k_gemm1(const float* __restrict__ x,
                                               const float* __restrict__ W1,
                                               const float* __restrict__ dis,
                                               float* __restrict__ h0s, int n) {
    __shared__ float lds[3 * G1_NODES * 33];
    float (*xt)[G1_NODES + 1] = (float (*)[G1_NODES + 1])lds;

    int tid = threadIdx.x;
    int wv = __builtin_amdgcn_readfirstlane(tid >> 6);
    int lane = tid & 63;
    int vbase = blockIdx.x * G1_NODES;

    float4 g[4];
#pragma unroll
    for (int it = 0; it < 4; ++it) {
        int f = it * 256 + tid;
        int nl = f >> 4, q = f & 15;
        int v = vbase + nl; if (v >= n) v = n - 1;
        g[it] = *reinterpret_cast<const float4*>(x + (size_t)v * IN_CH + q * 4);
    }

    float acc[HID];
#pragma unroll
    for (int c = 0; c < HID; ++c) acc[c] = 0.f;

    for (int ch = 0; ch < G1_NCHUNK; ++ch) {
        __syncthreads();
#pragma unroll
        for (int it = 0; it < 4; ++it) {
            int f = it * 256 + tid;
            int nl = f >> 4, q = f & 15;
            xt[q * 4 + 0][nl] = g[it].x;
            xt[q * 4 + 1][nl] = g[it].y;
            xt[q * 4 + 2][nl] = g[it].z;
            xt[q * 4 + 3][nl] = g[it].w;
        }
        __syncthreads();
        if (ch + 1 < G1_NCHUNK) {
#pragma unroll
            for (int it = 0; it < 4; ++it) {
                int f = it * 256 + tid;
                int nl = f >> 4, q = f & 15;
                int v = vbase + nl; if (v >= n) v = n - 1;
                g[it] = *reinterpret_cast<const float4*>(
                    x + (size_t)v * IN_CH + (ch + 1) * G1_KC + q * 4);
            }
        }
#pragma unroll
        for (int j = 0; j < 16; ++j) {
            int kk = ch * G1_KC + wv * 16 + j;
            float xs = xt[wv * 16 + j][lane];
            const float* wrow = W1 + kk * HID;
#pragma unroll
            for (int c = 0; c < HID; ++c)
                acc[c] = fmaf(xs, wrow[c], acc[c]);
        }
    }

    __syncthreads();
    if (wv > 0) {
        float* dst = lds + (wv - 1) * (G1_NODES * 33) + lane * 33;
#pragma unroll
        for (int c = 0; c < HID; ++c) dst[c] = acc[c];
    }
    __syncthreads();
    if (wv == 0) {
        int v = vbase + lane;
        if (v < n) {
#pragma unroll
            for (int p = 0; p < 3; ++p) {
                const float* srcp = lds + p * (G1_NODES * 33) + lane * 33;
#pragma unroll
                for (int c = 0; c < HID; ++c) acc[c] += srcp[c];
            }
            float dv = dis[v];
            float4* o = reinterpret_cast<float4*>(h0s + (size_t)v * HID);
#pragma unroll
            for (int q = 0; q < HID / 4; ++q)
                o[q] = make_float4(acc[q * 4] * dv, acc[q * 4 + 1] * dv,
                                   acc[q * 4 + 2] * dv, acc[q * 4 + 3] * dv);
        }
    }
}

// ---------------- aggregation 1: hs = dis * relu(dv*(sum h0s_u + h0s_v) + b1) ----------------
// 8 dests/wave, 8 lanes/dest (lane quad = 4 channels, float4 gather), unroll 8.

__global__ __launch_bounds__(256) void k_agg1(const float* __restrict__ h0s,
                                              const int* __restrict__ srow,
                                              const int* __restrict__ start,
                                              const int* __restrict__ deg,
                                              const float* __restrict__ dis,
                                              const float* __restrict__ b1,
                                              float* __restrict__ hs, int n) {
    int tid = threadIdx.x;
    int lane = tid & 63;
    int g = lane >> 3;
    int q = lane & 7;
    int wv = tid >> 6;
    int v = blockIdx.x * 32 + wv * 8 + g;
    if (v >= n) v = n - 1;
    int s = start[v], d = deg[v];
    float dv = dis[v];

    float4 a[8];
#pragma unroll
    for (int j = 0; j < 8; ++j) a[j] = make_float4(0.f, 0.f, 0.f, 0.f);

    for (int i = 0; i < d; i += 8) {
#pragma unroll
        for (int j = 0; j < 8; ++j) {
            int idx = i + j;
            bool valid = idx < d;
            int u = srow[s + (valid ? idx : 0)];
            const float4 gv = *reinterpret_cast<const float4*>(h0s + (size_t)u * HID + q * 4);
            float m = valid ? 1.f : 0.f;
            a[j].x = fmaf(m, gv.x, a[j].x);
            a[j].y = fmaf(m, gv.y, a[j].y);
            a[j].z = fmaf(m, gv.z, a[j].z);
            a[j].w = fmaf(m, gv.w, a[j].w);
        }
    }
    float4 acc;
    acc.x = ((a[0].x + a[1].x) + (a[2].x + a[3].x)) + ((a[4].x + a[5].x) + (a[6].x + a[7].x));
    acc.y = ((a[0].y + a[1].y) + (a[2].y + a[3].y)) + ((a[4].y + a[5].y) + (a[6].y + a[7].y));
    acc.z = ((a[0].z + a[1].z) + (a[2].z + a[3].z)) + ((a[4].z + a[5].z) + (a[6].z + a[7].z));
    acc.w = ((a[0].w + a[1].w) + (a[2].w + a[3].w)) + ((a[4].w + a[5].w) + (a[6].w + a[7].w));

    float4 self = *reinterpret_cast<const float4*>(h0s + (size_t)v * HID + q * 4);
    float4 bq = *reinterpret_cast<const float4*>(b1 + q * 4);
    float4 o;
    o.x = dv * fmaxf(0.f, fmaf(dv, acc.x + self.x, bq.x));
    o.y = dv * fmaxf(0.f, fmaf(dv, acc.y + self.y, bq.y));
    o.z = dv * fmaxf(0.f, fmaf(dv, acc.z + self.z, bq.z));
    o.w = dv * fmaxf(0.f, fmaf(dv, acc.w + self.w, bq.w));
    *reinterpret_cast<float4*>(hs + (size_t)v * HID + q * 4) = o;
}

// ---------------- aggregation 2: s = dv*(sum hs_u + hs_v); out = s @ [Wmu|Wlv] + bias ----------------

__global__ __launch_bounds__(256) void k_agg2(const float* __restrict__ hs,
                                              const int* __restrict__ srow,
                                              const int* __restrict__ start,
                                              const int* __restrict__ deg,
                                              const float* __restrict__ dis,
                                              const float* __restrict__ Wmu,
                                              const float* __restrict__ Wlv,
                                              const float* __restrict__ bmu,
                                              const float* __restrict__ blv,
                                              float* __restrict__ out, int n) {
    __shared__ float wc[32][36];      // combined [Wmu | Wlv], rows 16B-aligned
    __shared__ float svec[4][8][36];  // per-wave, per-group aggregated s vector
    int tid = threadIdx.x;
    for (int i = tid; i < 32 * 32; i += 256) {
        int k = i >> 5, c = i & 31;
        wc[k][c] = (c < OUT_CH) ? Wmu[k * OUT_CH + c] : Wlv[k * OUT_CH + (c - OUT_CH)];
    }

    int lane = tid & 63;
    int g = lane >> 3;
    int q = lane & 7;
    int wv = tid >> 6;
    int v = blockIdx.x * 32 + wv * 8 + g;
    if (v >= n) v = n - 1;
    int s = start[v], d = deg[v];
    float dv = dis[v];

    float4 a[8];
#pragma unroll
    for (int j = 0; j < 8; ++j) a[j] = make_float4(0.f, 0.f, 0.f, 0.f);

    for (int i = 0; i < d; i += 8) {
#pragma unroll
        for (int j = 0; j < 8; ++j) {
            int idx = i + j;
            bool valid = idx < d;
            int u = srow[s + (valid ? idx : 0)];
            const float4 gv = *reinterpret_cast<const float4*>(hs + (size_t)u * HID + q * 4);
            float m = valid ? 1.f : 0.f;
            a[j].x = fmaf(m, gv.x, a[j].x);
            a[j].y = fmaf(m, gv.y, a[j].y);
            a[j].z = fmaf(m, gv.z, a[j].z);
            a[j].w = fmaf(m, gv.w, a[j].w);
        }
    }
    float4 acc;
    acc.x = ((a[0].x + a[1].x) + (a[2].x + a[3].x)) + ((a[4].x + a[5].x) + (a[6].x + a[7].x));
    acc.y = ((a[0].y + a[1].y) + (a[2].y + a[3].y)) + ((a[4].y + a[5].y) + (a[6].y + a[7].y));
    acc.z = ((a[0].z + a[1].z) + (a[2].z + a[3].z)) + ((a[4].z + a[5].z) + (a[6].z + a[7].z));
    acc.w = ((a[0].w + a[1].w) + (a[2].w + a[3].w)) + ((a[4].w + a[5].w) + (a[6].w + a[7].w));

    float4 self = *reinterpret_cast<const float4*>(hs + (size_t)v * HID + q * 4);
    float4 sv;
    sv.x = dv * (acc.x + self.x);
    sv.y = dv * (acc.y + self.y);
    sv.z = dv * (acc.z + self.z);
    sv.w = dv * (acc.w + self.w);
    *reinterpret_cast<float4*>(&svec[wv][g][q * 4]) = sv;
    __syncthreads();

    // epilogue: lane computes its quad of out channels c' = q*4 .. q*4+3
    float4 o = make_float4(0.f, 0.f, 0.f, 0.f);
#pragma unroll
    for (int k = 0; k < 32; ++k) {
        float skv = svec[wv][g][k];
        const float4 wr = *reinterpret_cast<const float4*>(&wc[k][q * 4]);
        o.x = fmaf(skv, wr.x, o.x);
        o.y = fmaf(skv, wr.y, o.y);
        o.z = fmaf(skv, wr.z, o.z);
        o.w = fmaf(skv, wr.w, o.w);
    }
    if (q < 4) {
        float4 bb = *reinterpret_cast<const float4*>(bmu + q * 4);
        o.x += bb.x; o.y += bb.y; o.z += bb.z; o.w += bb.w;
        *reinterpret_cast<float4*>(out + (size_t)v * OUT_CH + q * 4) = o;
    } else {
        float4 bb = *reinterpret_cast<const float4*>(blv + (q - 4) * 4);
        o.x += bb.x; o.y += bb.y; o.z += bb.z; o.w += bb.w;
        *reinterpret_cast<float4*>(out + (size_t)N_NODES * OUT_CH + (size_t)v * OUT_CH + (q - 4) * 4) = o;
    }
}

// ---------------- launch ----------------

extern "C" void kernel_launch(void* const* d_in, const int* in_sizes, int n_in,
                              void* d_out, int out_size, void* d_ws, size_t ws_size,
                              hipStream_t stream) {
    const float* x   = (const float*)d_in[0];
    const int*   ei  = (const int*)d_in[1];
    const float* W1  = (const float*)d_in[2];
    const float* b1  = (const float*)d_in[3];
    const float* Wmu = (const float*)d_in[4];
    const float* bmu = (const float*)d_in[5];
    const float* Wlv = (const float*)d_in[6];
    const float* blv = (const float*)d_in[7];
    float* out = (float*)d_out;

    const int* row = ei;            // edge_index[0]
    const int* col = ei + E_EDGES;  // edge_index[1]

    char* w = (char*)d_ws;
    int*   bcnt   = (int*)w;  w += 1024;
    int*   bstart = (int*)w;  w += 1024;
    int*   bcur   = (int*)w;  w += 1024;
    int*   deg    = (int*)w;  w += (size_t)N_NODES * 4;
    float* dis    = (float*)w; w += (size_t)N_NODES * 4;
    int*   start  = (int*)w;  w += (size_t)N_NODES * 4;
    int*   srow   = (int*)w;  w += (size_t)E_EDGES * 4;
    unsigned* psrc = (unsigned*)w;                      // aliased with h0s (psrc dead after k_bsort)
    float* h0s    = (float*)w; w += (size_t)N_NODES * HID * 4;
    float* hs     = (float*)w; w += (size_t)N_NODES * HID * 4;

    hipMemsetAsync(bcnt, 0, 1024, stream);

    const int TB = 256;
    k_bcount<<<1024, TB, 0, stream>>>(col, bcnt, E_EDGES);
    k_bscan<<<1, 256, 0, stream>>>(bcnt, bstart, bcur);
    k_part<<<PART_BLOCKS, 256, 0, stream>>>(row, col, bcur, psrc, E_EDGES);
    k_bsort<<<B_BUCKETS, 512, 0, stream>>>(psrc, bstart, srow, deg, start, dis);
    k_gemm1<<<(N_NODES + G1_NODES - 1) / G1_NODES, 256, 0, stream>>>(x, W1, dis, h0s, N_NODES);
    k_agg1<<<(N_NODES + 31) / 32, TB, 0, stream>>>(h0s, srow, start, deg, dis, b1, hs, N_NODES);
    k_agg2<<<(N_NODES + 31) / 32, TB, 0, stream>>>(hs, srow, start, deg, dis, Wmu, Wlv, bmu, blv, out, N_NODES);
}